// Round 1
// baseline (1217.618 us; speedup 1.0000x reference)
//
#include <hip/hip_runtime.h>

// GraphSAGE 2-layer, N=100000 nodes, E=1600000 edges, 128 -> 64 -> 32.
// Strategy: transform-then-aggregate (mean commutes with linear), f32 atomics
// for scatter, on-device int32/int64 edge-dtype detection.

namespace {
constexpr int N = 100000;
constexpr int E = 1600000;
constexpr long long NF64 = (long long)N * 64;   // 6,400,000
constexpr long long NF32 = (long long)N * 32;   // 3,200,000

// workspace layout (in floats)
constexpr long long OFF_A   = 0;                // z1, then h        [N*64]
constexpr long long OFF_B   = NF64;             // r1, then z2|agg2  [N*64]
constexpr long long OFF_C   = 2 * NF64;         // agg1, then r2     [N*64]
constexpr long long OFF_DEG = 3 * NF64;         // deg               [N]
constexpr long long OFF_SRC = OFF_DEG + N;      // src (int)         [E]
constexpr long long OFF_DST = OFF_SRC + E;      // dst (int)         [E]
constexpr long long OFF_FLAG= OFF_DST + E;      // int flag          [1]
}

// ---------------- utility kernels ----------------

__global__ void zero_f4(float4* __restrict__ p, int n4, int* __restrict__ flag) {
    int i = blockIdx.x * blockDim.x + threadIdx.x;
    if (i < n4) p[i] = make_float4(0.f, 0.f, 0.f, 0.f);
    if (i == 0 && flag) *flag = 0;
}

// Detect edge dtype: read odd 32-bit words of the first E qwords.
// int64 data -> all high halves are 0 -> flag stays 0.
// int32 data -> those words are random node ids -> flag becomes 1.
__global__ void detect_dtype(const int* __restrict__ raw, int* __restrict__ flag) {
    int i = blockIdx.x * blockDim.x + threadIdx.x;
    int v = 0;
    if (i < E) v = raw[2 * i + 1];
    unsigned long long b = __ballot(v != 0);
    if ((threadIdx.x & 63) == 0 && b) atomicOr(flag, 1);
}

// Normalize edges to int32 src/dst arrays + degree histogram.
__global__ void norm_edges(const int* __restrict__ raw, int* __restrict__ src,
                           int* __restrict__ dst, float* __restrict__ deg,
                           const int* __restrict__ flag) {
    int e = blockIdx.x * blockDim.x + threadIdx.x;
    if (e >= E) return;
    int is32 = *flag;
    int s, d;
    if (is32) {                 // layout: [src(E) | dst(E)] as int32
        s = raw[e];
        d = raw[E + e];
    } else {                    // layout: [src(E) | dst(E)] as int64 (little-endian)
        s = raw[2 * (long long)e];
        d = raw[2 * ((long long)E + e)];
    }
    src[e] = s;
    dst[e] = d;
    atomicAdd(&deg[d], 1.0f);
}

// ---------------- layer 1 transform: z1 = x@W1l^T, r1 = x@W1r^T ----------------
// x: [N,128], W: [64,128]. Wave computes 64 outputs (one per lane) for 8 nodes.
__global__ __launch_bounds__(256) void transform1(
        const float* __restrict__ x, const float* __restrict__ W1l,
        const float* __restrict__ W1r, float* __restrict__ z1,
        float* __restrict__ r1) {
    __shared__ float4 wl4[32 * 64];   // wl4[k4*64 + j] = W1l[j][4k4 .. 4k4+3]
    __shared__ float4 wr4[32 * 64];
    const float4* Wl = (const float4*)W1l;   // [64][32] float4
    const float4* Wr = (const float4*)W1r;
    for (int idx = threadIdx.x; idx < 2048; idx += 256) {
        int j = idx & 63, k4 = idx >> 6;
        wl4[k4 * 64 + j] = Wl[j * 32 + k4];
        wr4[k4 * 64 + j] = Wr[j * 32 + k4];
    }
    __syncthreads();

    const int lane = threadIdx.x & 63;
    const int wid = blockIdx.x * (blockDim.x >> 6) + (threadIdx.x >> 6);
    const int nWaves = gridDim.x * (blockDim.x >> 6);
    const float4* x4 = (const float4*)x;     // [N][32]

    for (int base = wid * 8; base < N; base += nWaves * 8) {   // N % 8 == 0
        float accl[8], accr[8];
#pragma unroll
        for (int u = 0; u < 8; ++u) { accl[u] = 0.f; accr[u] = 0.f; }
        for (int k4 = 0; k4 < 32; ++k4) {
            float4 wlv = wl4[k4 * 64 + lane];
            float4 wrv = wr4[k4 * 64 + lane];
#pragma unroll
            for (int u = 0; u < 8; ++u) {
                float4 xq = x4[(size_t)(base + u) * 32 + k4];
                accl[u] += wlv.x * xq.x + wlv.y * xq.y + wlv.z * xq.z + wlv.w * xq.w;
                accr[u] += wrv.x * xq.x + wrv.y * xq.y + wrv.z * xq.z + wrv.w * xq.w;
            }
        }
#pragma unroll
        for (int u = 0; u < 8; ++u) {
            z1[(size_t)(base + u) * 64 + lane] = accl[u];
            r1[(size_t)(base + u) * 64 + lane] = accr[u];
        }
    }
}

// ---------------- layer 2 transform: z2 = h@W2l^T, r2 = h@W2r^T ----------------
// h: [N,64], W: [32,64]. Lanes 0..31 -> z2 cols, lanes 32..63 -> r2 cols.
__global__ __launch_bounds__(256) void transform2(
        const float* __restrict__ h, const float* __restrict__ W2l,
        const float* __restrict__ W2r, float* __restrict__ z2,
        float* __restrict__ r2) {
    __shared__ float4 wc4[16 * 64];   // wc4[k4*64 + j]
    const float4* Wl = (const float4*)W2l;   // [32][16] float4
    const float4* Wr = (const float4*)W2r;
    for (int idx = threadIdx.x; idx < 1024; idx += 256) {
        int j = idx & 63, k4 = idx >> 6;
        wc4[k4 * 64 + j] = (j < 32) ? Wl[j * 16 + k4] : Wr[(j - 32) * 16 + k4];
    }
    __syncthreads();

    const int lane = threadIdx.x & 63;
    const int wid = blockIdx.x * (blockDim.x >> 6) + (threadIdx.x >> 6);
    const int nWaves = gridDim.x * (blockDim.x >> 6);
    const float4* h4 = (const float4*)h;     // [N][16]

    for (int base = wid * 8; base < N; base += nWaves * 8) {
        float acc[8];
#pragma unroll
        for (int u = 0; u < 8; ++u) acc[u] = 0.f;
        for (int k4 = 0; k4 < 16; ++k4) {
            float4 wv = wc4[k4 * 64 + lane];
#pragma unroll
            for (int u = 0; u < 8; ++u) {
                float4 hq = h4[(size_t)(base + u) * 16 + k4];
                acc[u] += wv.x * hq.x + wv.y * hq.y + wv.z * hq.z + wv.w * hq.w;
            }
        }
#pragma unroll
        for (int u = 0; u < 8; ++u) {
            int n = base + u;
            if (lane < 32) z2[(size_t)n * 32 + lane] = acc[u];
            else           r2[(size_t)n * 32 + (lane - 32)] = acc[u];
        }
    }
}

// ---------------- scatter (segment-sum via atomics) ----------------

__global__ void scatter64(const int* __restrict__ src, const int* __restrict__ dst,
                          const float* __restrict__ z, float* __restrict__ agg) {
    long long t = (long long)blockIdx.x * blockDim.x + threadIdx.x;
    if (t >= (long long)E * 64) return;
    int e = (int)(t >> 6), j = (int)(t & 63);
    int s = src[e], d = dst[e];
    atomicAdd(&agg[(size_t)d * 64 + j], z[(size_t)s * 64 + j]);
}

__global__ void scatter32(const int* __restrict__ src, const int* __restrict__ dst,
                          const float* __restrict__ z, float* __restrict__ agg) {
    long long t = (long long)blockIdx.x * blockDim.x + threadIdx.x;
    if (t >= (long long)E * 32) return;
    int e = (int)(t >> 5), j = (int)(t & 31);
    int s = src[e], d = dst[e];
    atomicAdd(&agg[(size_t)d * 32 + j], z[(size_t)s * 32 + j]);
}

// ---------------- epilogues ----------------

__global__ void finish1(const float* __restrict__ agg1, const float* __restrict__ r1,
                        const float* __restrict__ deg, const float* __restrict__ b1,
                        float* __restrict__ h) {
    int i4 = blockIdx.x * blockDim.x + threadIdx.x;
    if (i4 >= NF64 / 4) return;
    long long i = (long long)i4 * 4;
    int n = (int)(i >> 6), j = (int)(i & 63);
    float dv = fmaxf(deg[n], 1.0f);
    float4 a = *(const float4*)(agg1 + i);
    float4 r = *(const float4*)(r1 + i);
    float4 b = *(const float4*)(b1 + j);
    float4 o;
    o.x = fmaxf(a.x / dv + b.x + r.x, 0.f);
    o.y = fmaxf(a.y / dv + b.y + r.y, 0.f);
    o.z = fmaxf(a.z / dv + b.z + r.z, 0.f);
    o.w = fmaxf(a.w / dv + b.w + r.w, 0.f);
    *(float4*)(h + i) = o;
}

__global__ void finish2(const float* __restrict__ agg2, const float* __restrict__ r2,
                        const float* __restrict__ deg, const float* __restrict__ b2,
                        float* __restrict__ out) {
    int i4 = blockIdx.x * blockDim.x + threadIdx.x;
    if (i4 >= NF32 / 4) return;
    long long i = (long long)i4 * 4;
    int n = (int)(i >> 5), j = (int)(i & 31);
    float dv = fmaxf(deg[n], 1.0f);
    float4 a = *(const float4*)(agg2 + i);
    float4 r = *(const float4*)(r2 + i);
    float4 b = *(const float4*)(b2 + j);
    float4 o;
    o.x = a.x / dv + b.x + r.x;
    o.y = a.y / dv + b.y + r.y;
    o.z = a.z / dv + b.z + r.z;
    o.w = a.w / dv + b.w + r.w;
    *(float4*)(out + i) = o;
}

// ---------------- launch ----------------

extern "C" void kernel_launch(void* const* d_in, const int* in_sizes, int n_in,
                              void* d_out, int out_size, void* d_ws, size_t ws_size,
                              hipStream_t stream) {
    const float* x    = (const float*)d_in[0];
    const int*   raw  = (const int*)d_in[1];
    const float* W1l  = (const float*)d_in[2];
    const float* b1   = (const float*)d_in[3];
    const float* W1r  = (const float*)d_in[4];
    const float* W2l  = (const float*)d_in[5];
    const float* b2   = (const float*)d_in[6];
    const float* W2r  = (const float*)d_in[7];
    float* out = (float*)d_out;

    float* ws   = (float*)d_ws;
    float* z1   = ws + OFF_A;            // then h
    float* h    = ws + OFF_A;
    float* r1   = ws + OFF_B;
    float* z2   = ws + OFF_B;            // reuses r1 space (after finish1)
    float* agg2 = ws + OFF_B + NF32;
    float* agg1 = ws + OFF_C;
    float* r2   = ws + OFF_C;            // reuses agg1 space (after finish1)
    float* deg  = ws + OFF_DEG;
    int*   src  = (int*)(ws + OFF_SRC);
    int*   dst  = (int*)(ws + OFF_DST);
    int*   flag = (int*)(ws + OFF_FLAG);

    // 1. zero agg1 + deg (contiguous) and flag
    {
        int n4 = (int)((NF64 + N) / 4);
        zero_f4<<<(n4 + 255) / 256, 256, 0, stream>>>((float4*)agg1, n4, flag);
    }
    // 2. detect edge dtype
    detect_dtype<<<(E + 255) / 256, 256, 0, stream>>>(raw, flag);
    // 3. normalize edges + degree
    norm_edges<<<(E + 255) / 256, 256, 0, stream>>>(raw, src, dst, deg, flag);
    // 4. layer-1 transforms
    transform1<<<1024, 256, 0, stream>>>(x, W1l, W1r, z1, r1);
    // 5. scatter-add z1[src] into agg1[dst]
    scatter64<<<(int)(((long long)E * 64 + 255) / 256), 256, 0, stream>>>(src, dst, z1, agg1);
    // 6. h = relu(agg1/deg + b1 + r1)  (h overwrites z1)
    finish1<<<(int)((NF64 / 4 + 255) / 256), 256, 0, stream>>>(agg1, r1, deg, b1, h);
    // 7. zero agg2
    {
        int n4 = (int)(NF32 / 4);
        zero_f4<<<(n4 + 255) / 256, 256, 0, stream>>>((float4*)agg2, n4, nullptr);
    }
    // 8. layer-2 transforms (z2 over r1 space, r2 over agg1 space)
    transform2<<<1024, 256, 0, stream>>>(h, W2l, W2r, z2, r2);
    // 9. scatter-add z2[src] into agg2[dst]
    scatter32<<<(int)(((long long)E * 32 + 255) / 256), 256, 0, stream>>>(src, dst, z2, agg2);
    // 10. out = agg2/deg + b2 + r2
    finish2<<<(int)((NF32 / 4 + 255) / 256), 256, 0, stream>>>(agg2, r2, deg, b2, out);
}

// Round 2
// 888.729 us; speedup vs baseline: 1.3701x; 1.3701x over previous
//
#include <hip/hip_runtime.h>

// GraphSAGE 2-layer, N=100000, E=1600000, 128 -> 64 -> 32.
// Round 2: transform-then-aggregate + CSR gather (no feature atomics).
// CSR built on-device: degree histogram -> 2-level scan -> counting-sort fill.
// Aggregation gathers z[src] per dst node and fuses mean+bias+root(+relu).

namespace {
constexpr int N = 100000;
constexpr int E = 1600000;
constexpr long long NF64 = (long long)N * 64;   // 6,400,000
constexpr long long NF32 = (long long)N * 32;
constexpr int NBLK = (N + 255) / 256;           // 391 scan blocks
}

// ---------------- CSR build ----------------

__global__ void zero_counts(int* __restrict__ counts, int* __restrict__ flag) {
    int i = blockIdx.x * blockDim.x + threadIdx.x;
    if (i < N) counts[i] = 0;
    if (i == 0) *flag = 0;
}

// int64 vs int32 edge dtype: odd 32-bit words of first E qwords are all zero
// iff data is int64 (node ids < 2^31).
__global__ void detect_dtype(const int* __restrict__ raw, int* __restrict__ flag) {
    int i = blockIdx.x * blockDim.x + threadIdx.x;
    int v = 0;
    if (i < E) v = raw[2 * i + 1];
    unsigned long long b = __ballot(v != 0);
    if ((threadIdx.x & 63) == 0 && b) atomicOr(flag, 1);
}

__global__ void count_deg(const int* __restrict__ raw, const int* __restrict__ flag,
                          int* __restrict__ counts) {
    int e = blockIdx.x * blockDim.x + threadIdx.x;
    if (e >= E) return;
    int is32 = *flag;
    int d = is32 ? raw[E + e] : raw[2 * ((long long)E + e)];
    atomicAdd(&counts[d], 1);
}

// Block-local inclusive scan (Hillis-Steele over 256 entries in LDS).
__global__ __launch_bounds__(256) void scan1(const int* __restrict__ counts,
                                             int* __restrict__ rowstart,
                                             int* __restrict__ bsum) {
    __shared__ int tmp[256];
    int t = threadIdx.x;
    int i = blockIdx.x * 256 + t;
    int v = (i < N) ? counts[i] : 0;
    tmp[t] = v;
    __syncthreads();
#pragma unroll
    for (int off = 1; off < 256; off <<= 1) {
        int a = (t >= off) ? tmp[t - off] : 0;
        __syncthreads();
        tmp[t] += a;
        __syncthreads();
    }
    if (i < N) rowstart[i] = tmp[t] - v;          // exclusive within block
    if (t == 255) bsum[blockIdx.x] = tmp[255];    // block total
}

__global__ __launch_bounds__(512) void scan2(int* __restrict__ bsum) {
    __shared__ int tmp[512];
    int t = threadIdx.x;
    int v = (t < NBLK) ? bsum[t] : 0;
    tmp[t] = v;
    __syncthreads();
#pragma unroll
    for (int off = 1; off < 512; off <<= 1) {
        int a = (t >= off) ? tmp[t - off] : 0;
        __syncthreads();
        tmp[t] += a;
        __syncthreads();
    }
    if (t < NBLK) bsum[t] = tmp[t] - v;           // exclusive block offsets
}

__global__ void scan3(int* __restrict__ rowstart, const int* __restrict__ bsum,
                      int* __restrict__ cursor) {
    int i = blockIdx.x * blockDim.x + threadIdx.x;
    if (i < N) {
        rowstart[i] += bsum[i >> 8];
        cursor[i] = 0;                            // counts recycled as cursor
    }
    if (i == 0) rowstart[N] = E;
}

__global__ void fill_csr(const int* __restrict__ raw, const int* __restrict__ flag,
                         const int* __restrict__ rowstart, int* __restrict__ cursor,
                         int* __restrict__ csr) {
    int e = blockIdx.x * blockDim.x + threadIdx.x;
    if (e >= E) return;
    int is32 = *flag;
    int s, d;
    if (is32) {
        s = raw[e];
        d = raw[E + e];
    } else {
        s = raw[2 * (long long)e];
        d = raw[2 * ((long long)E + e)];
    }
    int pos = rowstart[d] + atomicAdd(&cursor[d], 1);
    csr[pos] = s;
}

// ---------------- layer 1 transform: z1 = x@W1l^T, r1 = x@W1r^T ----------------
__global__ __launch_bounds__(256) void transform1(
        const float* __restrict__ x, const float* __restrict__ W1l,
        const float* __restrict__ W1r, float* __restrict__ z1,
        float* __restrict__ r1) {
    __shared__ float4 wl4[32 * 64];
    __shared__ float4 wr4[32 * 64];
    const float4* Wl = (const float4*)W1l;   // [64][32] float4
    const float4* Wr = (const float4*)W1r;
    for (int idx = threadIdx.x; idx < 2048; idx += 256) {
        int j = idx & 63, k4 = idx >> 6;
        wl4[k4 * 64 + j] = Wl[j * 32 + k4];
        wr4[k4 * 64 + j] = Wr[j * 32 + k4];
    }
    __syncthreads();

    const int lane = threadIdx.x & 63;
    const int wid = blockIdx.x * (blockDim.x >> 6) + (threadIdx.x >> 6);
    const int nWaves = gridDim.x * (blockDim.x >> 6);
    const float4* x4 = (const float4*)x;     // [N][32]

    for (int base = wid * 8; base < N; base += nWaves * 8) {   // N % 8 == 0
        float accl[8], accr[8];
#pragma unroll
        for (int u = 0; u < 8; ++u) { accl[u] = 0.f; accr[u] = 0.f; }
        for (int k4 = 0; k4 < 32; ++k4) {
            float4 wlv = wl4[k4 * 64 + lane];
            float4 wrv = wr4[k4 * 64 + lane];
#pragma unroll
            for (int u = 0; u < 8; ++u) {
                float4 xq = x4[(size_t)(base + u) * 32 + k4];
                accl[u] += wlv.x * xq.x + wlv.y * xq.y + wlv.z * xq.z + wlv.w * xq.w;
                accr[u] += wrv.x * xq.x + wrv.y * xq.y + wrv.z * xq.z + wrv.w * xq.w;
            }
        }
#pragma unroll
        for (int u = 0; u < 8; ++u) {
            z1[(size_t)(base + u) * 64 + lane] = accl[u];
            r1[(size_t)(base + u) * 64 + lane] = accr[u];
        }
    }
}

// ---------------- layer 2 transform: z2 = h@W2l^T, r2 = h@W2r^T ----------------
__global__ __launch_bounds__(256) void transform2(
        const float* __restrict__ h, const float* __restrict__ W2l,
        const float* __restrict__ W2r, float* __restrict__ z2,
        float* __restrict__ r2) {
    __shared__ float4 wc4[16 * 64];
    const float4* Wl = (const float4*)W2l;   // [32][16] float4
    const float4* Wr = (const float4*)W2r;
    for (int idx = threadIdx.x; idx < 1024; idx += 256) {
        int j = idx & 63, k4 = idx >> 6;
        wc4[k4 * 64 + j] = (j < 32) ? Wl[j * 16 + k4] : Wr[(j - 32) * 16 + k4];
    }
    __syncthreads();

    const int lane = threadIdx.x & 63;
    const int wid = blockIdx.x * (blockDim.x >> 6) + (threadIdx.x >> 6);
    const int nWaves = gridDim.x * (blockDim.x >> 6);
    const float4* h4 = (const float4*)h;     // [N][16]

    for (int base = wid * 8; base < N; base += nWaves * 8) {
        float acc[8];
#pragma unroll
        for (int u = 0; u < 8; ++u) acc[u] = 0.f;
        for (int k4 = 0; k4 < 16; ++k4) {
            float4 wv = wc4[k4 * 64 + lane];
#pragma unroll
            for (int u = 0; u < 8; ++u) {
                float4 hq = h4[(size_t)(base + u) * 16 + k4];
                acc[u] += wv.x * hq.x + wv.y * hq.y + wv.z * hq.z + wv.w * hq.w;
            }
        }
#pragma unroll
        for (int u = 0; u < 8; ++u) {
            int n = base + u;
            if (lane < 32) z2[(size_t)n * 32 + lane] = acc[u];
            else           r2[(size_t)n * 32 + (lane - 32)] = acc[u];
        }
    }
}

// ---------------- fused CSR-gather aggregation ----------------

// Layer 1: wave per node, lane = feature j (64 feats).
// h[n][j] = relu( mean_s z1[s][j] + b1[j] + r1[n][j] )
__global__ __launch_bounds__(256) void agg1_fused(
        const int* __restrict__ rowstart, const int* __restrict__ csr,
        const float* __restrict__ z1, const float* __restrict__ r1,
        const float* __restrict__ b1, float* __restrict__ h) {
    const int n = blockIdx.x * 4 + (threadIdx.x >> 6);
    if (n >= N) return;
    const int j = threadIdx.x & 63;
    const int beg = rowstart[n], end = rowstart[n + 1];
    float s = 0.f;
    int p = beg;
    for (; p + 4 <= end; p += 4) {
        int c0 = csr[p], c1 = csr[p + 1], c2 = csr[p + 2], c3 = csr[p + 3];
        s += z1[(size_t)c0 * 64 + j] + z1[(size_t)c1 * 64 + j]
           + z1[(size_t)c2 * 64 + j] + z1[(size_t)c3 * 64 + j];
    }
    for (; p < end; ++p) s += z1[(size_t)csr[p] * 64 + j];
    float m = (end > beg) ? s / (float)(end - beg) : 0.f;
    size_t o = (size_t)n * 64 + j;
    h[o] = fmaxf(m + b1[j] + r1[o], 0.f);
}

// Layer 2: half-wave per node (32 feats), wave handles 2 nodes.
__global__ __launch_bounds__(256) void agg2_fused(
        const int* __restrict__ rowstart, const int* __restrict__ csr,
        const float* __restrict__ z2, const float* __restrict__ r2,
        const float* __restrict__ b2, float* __restrict__ out) {
    const int wid = blockIdx.x * 4 + (threadIdx.x >> 6);
    const int n = wid * 2 + ((threadIdx.x >> 5) & 1);
    if (n >= N) return;
    const int j = threadIdx.x & 31;
    const int beg = rowstart[n], end = rowstart[n + 1];
    float s = 0.f;
    int p = beg;
    for (; p + 4 <= end; p += 4) {
        int c0 = csr[p], c1 = csr[p + 1], c2 = csr[p + 2], c3 = csr[p + 3];
        s += z2[(size_t)c0 * 32 + j] + z2[(size_t)c1 * 32 + j]
           + z2[(size_t)c2 * 32 + j] + z2[(size_t)c3 * 32 + j];
    }
    for (; p < end; ++p) s += z2[(size_t)csr[p] * 32 + j];
    float m = (end > beg) ? s / (float)(end - beg) : 0.f;
    size_t o = (size_t)n * 32 + j;
    out[o] = m + b2[j] + r2[o];
}

// ---------------- launch ----------------

extern "C" void kernel_launch(void* const* d_in, const int* in_sizes, int n_in,
                              void* d_out, int out_size, void* d_ws, size_t ws_size,
                              hipStream_t stream) {
    const float* x    = (const float*)d_in[0];
    const int*   raw  = (const int*)d_in[1];
    const float* W1l  = (const float*)d_in[2];
    const float* b1   = (const float*)d_in[3];
    const float* W1r  = (const float*)d_in[4];
    const float* W2l  = (const float*)d_in[5];
    const float* b2   = (const float*)d_in[6];
    const float* W2r  = (const float*)d_in[7];
    float* out = (float*)d_out;

    float* ws = (float*)d_ws;
    float* z1 = ws;                    // [N*64]
    float* r1 = ws + NF64;             // [N*64]
    float* h  = ws + 2 * NF64;         // [N*64]
    float* z2 = ws;                    // reuse z1 space [N*32]
    float* r2 = ws + NF32;             // reuse z1 space [N*32]

    int* ibase    = (int*)(ws + 3 * NF64);
    int* counts   = ibase;                   // [N], recycled as cursor
    int* rowstart = ibase + N;               // [N+1]
    int* bsum     = ibase + 2 * N + 1;       // [512]
    int* csr      = ibase + 2 * N + 1 + 512; // [E]
    int* flag     = csr + E;                 // [1]

    const int eb = (E + 255) / 256;

    zero_counts<<<NBLK, 256, 0, stream>>>(counts, flag);
    detect_dtype<<<eb, 256, 0, stream>>>(raw, flag);
    count_deg<<<eb, 256, 0, stream>>>(raw, flag, counts);
    scan1<<<NBLK, 256, 0, stream>>>(counts, rowstart, bsum);
    scan2<<<1, 512, 0, stream>>>(bsum);
    scan3<<<NBLK, 256, 0, stream>>>(rowstart, bsum, counts);
    fill_csr<<<eb, 256, 0, stream>>>(raw, flag, rowstart, counts, csr);

    transform1<<<1024, 256, 0, stream>>>(x, W1l, W1r, z1, r1);
    agg1_fused<<<(N + 3) / 4, 256, 0, stream>>>(rowstart, csr, z1, r1, b1, h);

    transform2<<<1024, 256, 0, stream>>>(h, W2l, W2r, z2, r2);
    agg2_fused<<<(N + 7) / 8, 256, 0, stream>>>(rowstart, csr, z2, r2, b2, out);
}

// Round 3
// 583.210 us; speedup vs baseline: 2.0878x; 1.5239x over previous
//
#include <hip/hip_runtime.h>

// GraphSAGE 2-layer, N=100000, E=1600000, 128 -> 64 -> 32.
// Round 3: same as round 2 (transform-then-aggregate + CSR gather) but the
// edge-dtype detection is a single-block sampling kernel (the round-2 version
// fired 25K same-address atomicOr -> 286 us serialization storm).

namespace {
constexpr int N = 100000;
constexpr int E = 1600000;
constexpr long long NF64 = (long long)N * 64;   // 6,400,000
constexpr long long NF32 = (long long)N * 32;
constexpr int NBLK = (N + 255) / 256;           // 391 scan blocks
}

// ---------------- CSR build ----------------

// int64 vs int32 edge dtype: high 32-bit words of int64 entries are all zero
// (node ids < 2^31). For int32 data those words are random node ids, so
// sampling 16384 of them misdetects with probability (1e-5)^16384 = 0.
// Single block, ballot reduce, one plain store -> no atomic storm.
__global__ __launch_bounds__(256) void detect_dtype(const int* __restrict__ raw,
                                                    int* __restrict__ flag) {
    int any = 0;
#pragma unroll
    for (int k = 0; k < 64; ++k) {
        int i = threadIdx.x + k * 256;          // first 16384 qwords
        any |= raw[2 * i + 1];
    }
    unsigned long long b = __ballot(any != 0);
    __shared__ int acc[4];
    int w = threadIdx.x >> 6;
    if ((threadIdx.x & 63) == 0) acc[w] = (b != 0ULL) ? 1 : 0;
    __syncthreads();
    if (threadIdx.x == 0) *flag = acc[0] | acc[1] | acc[2] | acc[3];
}

__global__ void zero_counts(int* __restrict__ counts) {
    int i = blockIdx.x * blockDim.x + threadIdx.x;
    if (i < N) counts[i] = 0;
}

__global__ void count_deg(const int* __restrict__ raw, const int* __restrict__ flag,
                          int* __restrict__ counts) {
    int e = blockIdx.x * blockDim.x + threadIdx.x;
    if (e >= E) return;
    int is32 = *flag;
    int d = is32 ? raw[E + e] : raw[2 * ((long long)E + e)];
    atomicAdd(&counts[d], 1);
}

// Block-local inclusive scan (Hillis-Steele over 256 entries in LDS).
__global__ __launch_bounds__(256) void scan1(const int* __restrict__ counts,
                                             int* __restrict__ rowstart,
                                             int* __restrict__ bsum) {
    __shared__ int tmp[256];
    int t = threadIdx.x;
    int i = blockIdx.x * 256 + t;
    int v = (i < N) ? counts[i] : 0;
    tmp[t] = v;
    __syncthreads();
#pragma unroll
    for (int off = 1; off < 256; off <<= 1) {
        int a = (t >= off) ? tmp[t - off] : 0;
        __syncthreads();
        tmp[t] += a;
        __syncthreads();
    }
    if (i < N) rowstart[i] = tmp[t] - v;          // exclusive within block
    if (t == 255) bsum[blockIdx.x] = tmp[255];    // block total
}

__global__ __launch_bounds__(512) void scan2(int* __restrict__ bsum) {
    __shared__ int tmp[512];
    int t = threadIdx.x;
    int v = (t < NBLK) ? bsum[t] : 0;
    tmp[t] = v;
    __syncthreads();
#pragma unroll
    for (int off = 1; off < 512; off <<= 1) {
        int a = (t >= off) ? tmp[t - off] : 0;
        __syncthreads();
        tmp[t] += a;
        __syncthreads();
    }
    if (t < NBLK) bsum[t] = tmp[t] - v;           // exclusive block offsets
}

__global__ void scan3(int* __restrict__ rowstart, const int* __restrict__ bsum,
                      int* __restrict__ cursor) {
    int i = blockIdx.x * blockDim.x + threadIdx.x;
    if (i < N) {
        rowstart[i] += bsum[i >> 8];
        cursor[i] = 0;                            // counts recycled as cursor
    }
    if (i == 0) rowstart[N] = E;
}

__global__ void fill_csr(const int* __restrict__ raw, const int* __restrict__ flag,
                         const int* __restrict__ rowstart, int* __restrict__ cursor,
                         int* __restrict__ csr) {
    int e = blockIdx.x * blockDim.x + threadIdx.x;
    if (e >= E) return;
    int is32 = *flag;
    int s, d;
    if (is32) {
        s = raw[e];
        d = raw[E + e];
    } else {
        s = raw[2 * (long long)e];
        d = raw[2 * ((long long)E + e)];
    }
    int pos = rowstart[d] + atomicAdd(&cursor[d], 1);
    csr[pos] = s;
}

// ---------------- layer 1 transform: z1 = x@W1l^T, r1 = x@W1r^T ----------------
__global__ __launch_bounds__(256) void transform1(
        const float* __restrict__ x, const float* __restrict__ W1l,
        const float* __restrict__ W1r, float* __restrict__ z1,
        float* __restrict__ r1) {
    __shared__ float4 wl4[32 * 64];
    __shared__ float4 wr4[32 * 64];
    const float4* Wl = (const float4*)W1l;   // [64][32] float4
    const float4* Wr = (const float4*)W1r;
    for (int idx = threadIdx.x; idx < 2048; idx += 256) {
        int j = idx & 63, k4 = idx >> 6;
        wl4[k4 * 64 + j] = Wl[j * 32 + k4];
        wr4[k4 * 64 + j] = Wr[j * 32 + k4];
    }
    __syncthreads();

    const int lane = threadIdx.x & 63;
    const int wid = blockIdx.x * (blockDim.x >> 6) + (threadIdx.x >> 6);
    const int nWaves = gridDim.x * (blockDim.x >> 6);
    const float4* x4 = (const float4*)x;     // [N][32]

    for (int base = wid * 8; base < N; base += nWaves * 8) {   // N % 8 == 0
        float accl[8], accr[8];
#pragma unroll
        for (int u = 0; u < 8; ++u) { accl[u] = 0.f; accr[u] = 0.f; }
        for (int k4 = 0; k4 < 32; ++k4) {
            float4 wlv = wl4[k4 * 64 + lane];
            float4 wrv = wr4[k4 * 64 + lane];
#pragma unroll
            for (int u = 0; u < 8; ++u) {
                float4 xq = x4[(size_t)(base + u) * 32 + k4];
                accl[u] += wlv.x * xq.x + wlv.y * xq.y + wlv.z * xq.z + wlv.w * xq.w;
                accr[u] += wrv.x * xq.x + wrv.y * xq.y + wrv.z * xq.z + wrv.w * xq.w;
            }
        }
#pragma unroll
        for (int u = 0; u < 8; ++u) {
            z1[(size_t)(base + u) * 64 + lane] = accl[u];
            r1[(size_t)(base + u) * 64 + lane] = accr[u];
        }
    }
}

// ---------------- layer 2 transform: z2 = h@W2l^T, r2 = h@W2r^T ----------------
__global__ __launch_bounds__(256) void transform2(
        const float* __restrict__ h, const float* __restrict__ W2l,
        const float* __restrict__ W2r, float* __restrict__ z2,
        float* __restrict__ r2) {
    __shared__ float4 wc4[16 * 64];
    const float4* Wl = (const float4*)W2l;   // [32][16] float4
    const float4* Wr = (const float4*)W2r;
    for (int idx = threadIdx.x; idx < 1024; idx += 256) {
        int j = idx & 63, k4 = idx >> 6;
        wc4[k4 * 64 + j] = (j < 32) ? Wl[j * 16 + k4] : Wr[(j - 32) * 16 + k4];
    }
    __syncthreads();

    const int lane = threadIdx.x & 63;
    const int wid = blockIdx.x * (blockDim.x >> 6) + (threadIdx.x >> 6);
    const int nWaves = gridDim.x * (blockDim.x >> 6);
    const float4* h4 = (const float4*)h;     // [N][16]

    for (int base = wid * 8; base < N; base += nWaves * 8) {
        float acc[8];
#pragma unroll
        for (int u = 0; u < 8; ++u) acc[u] = 0.f;
        for (int k4 = 0; k4 < 16; ++k4) {
            float4 wv = wc4[k4 * 64 + lane];
#pragma unroll
            for (int u = 0; u < 8; ++u) {
                float4 hq = h4[(size_t)(base + u) * 16 + k4];
                acc[u] += wv.x * hq.x + wv.y * hq.y + wv.z * hq.z + wv.w * hq.w;
            }
        }
#pragma unroll
        for (int u = 0; u < 8; ++u) {
            int n = base + u;
            if (lane < 32) z2[(size_t)n * 32 + lane] = acc[u];
            else           r2[(size_t)n * 32 + (lane - 32)] = acc[u];
        }
    }
}

// ---------------- fused CSR-gather aggregation ----------------

// Layer 1: wave per node, lane = feature j (64 feats).
__global__ __launch_bounds__(256) void agg1_fused(
        const int* __restrict__ rowstart, const int* __restrict__ csr,
        const float* __restrict__ z1, const float* __restrict__ r1,
        const float* __restrict__ b1, float* __restrict__ h) {
    const int n = blockIdx.x * 4 + (threadIdx.x >> 6);
    if (n >= N) return;
    const int j = threadIdx.x & 63;
    const int beg = rowstart[n], end = rowstart[n + 1];
    float s = 0.f;
    int p = beg;
    for (; p + 4 <= end; p += 4) {
        int c0 = csr[p], c1 = csr[p + 1], c2 = csr[p + 2], c3 = csr[p + 3];
        s += z1[(size_t)c0 * 64 + j] + z1[(size_t)c1 * 64 + j]
           + z1[(size_t)c2 * 64 + j] + z1[(size_t)c3 * 64 + j];
    }
    for (; p < end; ++p) s += z1[(size_t)csr[p] * 64 + j];
    float m = (end > beg) ? s / (float)(end - beg) : 0.f;
    size_t o = (size_t)n * 64 + j;
    h[o] = fmaxf(m + b1[j] + r1[o], 0.f);
}

// Layer 2: half-wave per node (32 feats), wave handles 2 nodes.
__global__ __launch_bounds__(256) void agg2_fused(
        const int* __restrict__ rowstart, const int* __restrict__ csr,
        const float* __restrict__ z2, const float* __restrict__ r2,
        const float* __restrict__ b2, float* __restrict__ out) {
    const int wid = blockIdx.x * 4 + (threadIdx.x >> 6);
    const int n = wid * 2 + ((threadIdx.x >> 5) & 1);
    if (n >= N) return;
    const int j = threadIdx.x & 31;
    const int beg = rowstart[n], end = rowstart[n + 1];
    float s = 0.f;
    int p = beg;
    for (; p + 4 <= end; p += 4) {
        int c0 = csr[p], c1 = csr[p + 1], c2 = csr[p + 2], c3 = csr[p + 3];
        s += z2[(size_t)c0 * 32 + j] + z2[(size_t)c1 * 32 + j]
           + z2[(size_t)c2 * 32 + j] + z2[(size_t)c3 * 32 + j];
    }
    for (; p < end; ++p) s += z2[(size_t)csr[p] * 32 + j];
    float m = (end > beg) ? s / (float)(end - beg) : 0.f;
    size_t o = (size_t)n * 32 + j;
    out[o] = m + b2[j] + r2[o];
}

// ---------------- launch ----------------

extern "C" void kernel_launch(void* const* d_in, const int* in_sizes, int n_in,
                              void* d_out, int out_size, void* d_ws, size_t ws_size,
                              hipStream_t stream) {
    const float* x    = (const float*)d_in[0];
    const int*   raw  = (const int*)d_in[1];
    const float* W1l  = (const float*)d_in[2];
    const float* b1   = (const float*)d_in[3];
    const float* W1r  = (const float*)d_in[4];
    const float* W2l  = (const float*)d_in[5];
    const float* b2   = (const float*)d_in[6];
    const float* W2r  = (const float*)d_in[7];
    float* out = (float*)d_out;

    float* ws = (float*)d_ws;
    float* z1 = ws;                    // [N*64]
    float* r1 = ws + NF64;             // [N*64]
    float* h  = ws + 2 * NF64;         // [N*64]
    float* z2 = ws;                    // reuse z1 space [N*32]
    float* r2 = ws + NF32;             // reuse z1 space [N*32]

    int* ibase    = (int*)(ws + 3 * NF64);
    int* counts   = ibase;                   // [N], recycled as cursor
    int* rowstart = ibase + N;               // [N+1]
    int* bsum     = ibase + 2 * N + 1;       // [512]
    int* csr      = ibase + 2 * N + 1 + 512; // [E]
    int* flag     = csr + E;                 // [1]

    const int eb = (E + 255) / 256;

    detect_dtype<<<1, 256, 0, stream>>>(raw, flag);
    zero_counts<<<NBLK, 256, 0, stream>>>(counts);
    count_deg<<<eb, 256, 0, stream>>>(raw, flag, counts);
    scan1<<<NBLK, 256, 0, stream>>>(counts, rowstart, bsum);
    scan2<<<1, 512, 0, stream>>>(bsum);
    scan3<<<NBLK, 256, 0, stream>>>(rowstart, bsum, counts);
    fill_csr<<<eb, 256, 0, stream>>>(raw, flag, rowstart, counts, csr);

    transform1<<<1024, 256, 0, stream>>>(x, W1l, W1r, z1, r1);
    agg1_fused<<<(N + 3) / 4, 256, 0, stream>>>(rowstart, csr, z1, r1, b1, h);

    transform2<<<1024, 256, 0, stream>>>(h, W2l, W2r, z2, r2);
    agg2_fused<<<(N + 7) / 8, 256, 0, stream>>>(rowstart, csr, z2, r2, b2, out);
}